// Round 8
// baseline (158.731 us; speedup 1.0000x reference)
//
#include <hip/hip_runtime.h>
#include <math.h>

// spaceGraph via f16 MFMA, round 9.
// R8 post-mortem: prefetch pipeline was right, but tile1's P2 re-read x from
// global ~4000cy after the prefetch -> lines evicted -> +24MB HBM on the
// critical path (FETCH 33->57MB). R9 removes the double-read entirely:
//  - P2 A-frags from LDS Xh (x is read EXACTLY ONCE per tile, via prefetch).
//  - u,v computed by the SAME MFMA as T: G buffer extended to 80 rows with
//    row64 = g2 (-> v in lane col0), row65 = g1 (-> u in lane col1), rows
//    66..79 = 0. One extra nt iteration (+4 MFMA/wave) replaces all VALU
//    dot/reduce machinery. u/v stored to Xt row-pads (f32 slots).
//  - barriers: B1 post-staging (Xh/Xt), B2 post-P2 (cross-wave v). Both
//    lgkm-only s_barrier -- vmcnt NEVER drained mid-kernel, so the tile1
//    prefetch (issued right after B2, no younger global loads) rides across
//    P3..P5 (~2.5Kcy >> 900cy HBM).
//  - otherwise R5 structure: 256 thr, 4 waves x 32 rows, padded strides,
//    exp2 softmax, 54272B LDS -> 3 blocks/CU.

namespace {
constexpr int H = 8, NV = 128, HEAD = 64, B = 4, L = 8192;
constexpr int P = L / NV;        // 64
constexpr int D = H * HEAD;      // 512
constexpr int RS = P * D;        // 32768 floats between vars j -> j+1
constexpr int NT2 = (B * H * P) / 2;   // 1024 blocks, 2 tiles each

constexpr int XT_S = 136;        // Xt row stride (halfs); 64 rows (dims)
constexpr int XH_S = 72;         // Xh row stride (halfs); 128 rows (vars)
constexpr int TA_S = 72;         // T / A_half row stride (halfs); 128 rows

typedef _Float16 half8  __attribute__((ext_vector_type(8)));
typedef _Float16 half4h __attribute__((ext_vector_type(4)));
typedef _Float16 half2v __attribute__((ext_vector_type(2)));
typedef float    floatx4 __attribute__((ext_vector_type(4)));

__device__ __forceinline__ floatx4 mfma16(half8 a, half8 b, floatx4 c) {
    return __builtin_amdgcn_mfma_f32_16x16x32_f16(a, b, c, 0, 0, 0);
}

// u[128] in Xt row-pads of rows 0..31, v[128] in rows 32..63 (f32 slots).
__device__ __forceinline__ float& uslot(_Float16* xt, int j) {
    return ((float*)(xt + (j >> 2) * XT_S + 128))[j & 3];
}
__device__ __forceinline__ float& vslot(_Float16* xt, int j) {
    return ((float*)(xt + (32 + (j >> 2)) * XT_S + 128))[j & 3];
}

// ---- pre-pass: gxh[80][64] f16: rows 0..63 = G^T (gxh[e][d] = sum_n
// w1[n][d]w2[n][e]); row 64 = g2 (d -> sum_n w2[n][d]b1[n]); row 65 = g1
// (d -> sum_n w1[n][d]b2[n]); rows 66..79 = 0.  cf = b1.b2 ----
__global__ __launch_bounds__(256) void pack_g(
    const float* __restrict__ w1, const float* __restrict__ w2,
    const float* __restrict__ b1, const float* __restrict__ b2,
    _Float16* __restrict__ gxh, float* __restrict__ cf)
{
    const int t = threadIdx.x;
    if (blockIdx.x == 16) {
        for (int z = t; z < 14 * 64; z += 256) gxh[66 * 64 + z] = (_Float16)0.f;
        if (t < 64) {
            float a = 0.f;
            #pragma unroll 8
            for (int n = 0; n < 64; ++n) a = fmaf(w2[n * 64 + t], b1[n], a);
            gxh[64 * 64 + t] = (_Float16)a;      // g2 -> v
        } else if (t < 128) {
            const int d = t - 64;
            float a = 0.f;
            #pragma unroll 8
            for (int n = 0; n < 64; ++n) a = fmaf(w1[n * 64 + d], b2[n], a);
            gxh[65 * 64 + d] = (_Float16)a;      // g1 -> u
        } else if (t == 128) {
            float a = 0.f;
            for (int n = 0; n < 64; ++n) a = fmaf(b1[n], b2[n], a);
            cf[0] = a;
        }
        return;
    }
    const int gid = blockIdx.x * 256 + t;
    const int d = gid & 63, e = gid >> 6;
    float a = 0.f;
    #pragma unroll 8
    for (int n = 0; n < 64; ++n) a = fmaf(w1[n * 64 + d], w2[n * 64 + e], a);
    gxh[e * 64 + d] = (_Float16)a;
}

__global__ __launch_bounds__(256, 3) void space_graph_mfma9(
    const float* __restrict__ x, const _Float16* __restrict__ gxh,
    const float* __restrict__ cf, float* __restrict__ out)
{
    // 64*136 + 128*72 + 128*72 = 27136 halfs = 54272 B -> 3 blocks/CU
    __shared__ _Float16 lds[64 * XT_S + NV * XH_S + NV * TA_S];
    _Float16* Xt = lds;                  // X^T [dim][var] (+u/v in row pads)
    _Float16* Xh = lds + 64 * XT_S;      // X   [var][dim] f16
    _Float16* TA = Xh + NV * XH_S;       // T (ph2-3), A_half (ph4-5)

    const int t    = threadIdx.x;
    const int lane = t & 63;
    const int w    = t >> 6;             // wave -> owns S/O rows 32w..32w+31
    const int col  = lane & 15;
    const int quad = lane >> 4;
    const int c    = t & 15;             // staging: float4 column
    const int ttv  = t >> 4;             // staging: row-pair selector 0..15

    const int blk = blockIdx.x;
    const int ti0 = blk, ti1 = blk + NT2;
    const size_t base0 =
        ((size_t)(ti0 >> 9) * L + (size_t)(ti0 & (P - 1))) * D + (size_t)((ti0 >> 6) & (H - 1)) * HEAD;
    const size_t base1 =
        ((size_t)(ti1 >> 9) * L + (size_t)(ti1 & (P - 1))) * D + (size_t)((ti1 >> 6) & (H - 1)) * HEAD;

    const float cc = cf[0];

    // ---- prefetch tile 0 staging loads into registers ----
    float4 pf[8];
    #pragma unroll
    for (int it = 0; it < 4; ++it) {
        const int j0 = 2 * (ttv + 16 * it);
        pf[2 * it]     = *(const float4*)(x + base0 + (size_t)j0 * RS + c * 4);
        pf[2 * it + 1] = *(const float4*)(x + base0 + (size_t)(j0 + 1) * RS + c * 4);
    }

    #pragma unroll
    for (int tile = 0; tile < 2; ++tile) {
        const size_t base = (tile == 0) ? base0 : base1;

        if (tile == 1) {   // B0: previous tile's LDS readers done (lgkm only)
            asm volatile("s_waitcnt lgkmcnt(0)" ::: "memory");
            __builtin_amdgcn_s_barrier();
            __builtin_amdgcn_sched_barrier(0);
        }

        // ---- Stage: prefetched regs -> Xt (transposed) + Xh (row-major) ----
        #pragma unroll
        for (int it = 0; it < 4; ++it) {
            const int j0 = 2 * (ttv + 16 * it);
            const float4 v0 = pf[2 * it];
            const float4 v1 = pf[2 * it + 1];
            const float va[4] = {v0.x, v0.y, v0.z, v0.w};
            const float vb[4] = {v1.x, v1.y, v1.z, v1.w};
            half4h ra, rb;
            #pragma unroll
            for (int q = 0; q < 4; ++q) {
                const _Float16 ha = (_Float16)va[q];
                const _Float16 hb = (_Float16)vb[q];
                ra[q] = ha; rb[q] = hb;
                half2v pr; pr[0] = ha; pr[1] = hb;
                *(half2v*)&Xt[(4 * c + q) * XT_S + j0] = pr;
            }
            *(half4h*)&Xh[(size_t)j0 * XH_S + 4 * c] = ra;
            *(half4h*)&Xh[(size_t)(j0 + 1) * XH_S + 4 * c] = rb;
        }

        // ---- B1: staging visible to all waves (lgkm only) ----
        asm volatile("s_waitcnt lgkmcnt(0)" ::: "memory");
        __builtin_amdgcn_s_barrier();
        __builtin_amdgcn_sched_barrier(0);

        // ---- Phase 2: [T | v u] = Xh * [G | g2 g1]  (A-frags from LDS) ----
        floatx4 tacc[2][5];
        #pragma unroll
        for (int mt = 0; mt < 2; ++mt)
            #pragma unroll
            for (int nt = 0; nt < 5; ++nt) tacc[mt][nt] = (floatx4)0.0f;

        half8 axf[2][2];
        #pragma unroll
        for (int ks = 0; ks < 2; ++ks)
            #pragma unroll
            for (int mt = 0; mt < 2; ++mt)
                axf[mt][ks] = *(const half8*)&Xh[(32 * w + 16 * mt + col) * XH_S + quad * 8 + 32 * ks];

        #pragma unroll
        for (int ks = 0; ks < 2; ++ks)
            #pragma unroll
            for (int nt = 0; nt < 5; ++nt) {
                const half8 gb8 = *(const half8*)&gxh[(col + 16 * nt) * HEAD + quad * 8 + 32 * ks];
                #pragma unroll
                for (int mt = 0; mt < 2; ++mt)
                    tacc[mt][nt] = mfma16(axf[mt][ks], gb8, tacc[mt][nt]);
            }

        // u/v (from the nt=4 column block) -> Xt row-pad slots
        #pragma unroll
        for (int mt = 0; mt < 2; ++mt)
            #pragma unroll
            for (int r = 0; r < 4; ++r) {
                const int R = 32 * w + 16 * mt + quad * 4 + r;
                if (col == 0) vslot(Xt, R) = tacc[mt][4][r];
                if (col == 1) uslot(Xt, R) = tacc[mt][4][r];
            }

        // T store (wave-private rows)
        #pragma unroll
        for (int mt = 0; mt < 2; ++mt)
            #pragma unroll
            for (int r = 0; r < 4; ++r) {
                const int R = 32 * w + 16 * mt + quad * 4 + r;
                _Float16* trow = &TA[R * TA_S + col];
                #pragma unroll
                for (int nt = 0; nt < 4; ++nt)
                    trow[nt * 16] = (_Float16)(tacc[mt][nt][r]);
            }

        // ---- B2: cross-wave v (and T ordering); lgkm only ----
        asm volatile("s_waitcnt lgkmcnt(0)" ::: "memory");
        __builtin_amdgcn_s_barrier();
        __builtin_amdgcn_sched_barrier(0);

        // ---- issue tile1 prefetch: last global loads of tile0; ride P3-P5 ----
        if (tile == 0) {
            #pragma unroll
            for (int it = 0; it < 4; ++it) {
                const int j0 = 2 * (ttv + 16 * it);
                pf[2 * it]     = *(const float4*)(x + base1 + (size_t)j0 * RS + c * 4);
                pf[2 * it + 1] = *(const float4*)(x + base1 + (size_t)(j0 + 1) * RS + c * 4);
            }
            __builtin_amdgcn_sched_barrier(0);
        }

        // ---- Phase 3: S = T*Xh^T + (u_i + v_j + c) via accumulator init ----
        float ucr[2][4];
        #pragma unroll
        for (int mt = 0; mt < 2; ++mt)
            #pragma unroll
            for (int r = 0; r < 4; ++r)
                ucr[mt][r] = uslot(Xt, 32 * w + 16 * mt + quad * 4 + r) + cc;
        float vrow[8];
        #pragma unroll
        for (int nt = 0; nt < 8; ++nt) vrow[nt] = vslot(Xt, col + 16 * nt);

        floatx4 sacc[2][8];
        #pragma unroll
        for (int mt = 0; mt < 2; ++mt)
            #pragma unroll
            for (int nt = 0; nt < 8; ++nt)
                #pragma unroll
                for (int r = 0; r < 4; ++r)
                    sacc[mt][nt][r] = ucr[mt][r] + vrow[nt];

        #pragma unroll
        for (int ks = 0; ks < 2; ++ks) {
            half8 taf[2];
            #pragma unroll
            for (int mt = 0; mt < 2; ++mt)
                taf[mt] = *(const half8*)&TA[(32 * w + 16 * mt + col) * TA_S + quad * 8 + 32 * ks];
            #pragma unroll
            for (int nt = 0; nt < 8; ++nt) {
                const half8 xb = *(const half8*)&Xh[(col + 16 * nt) * XH_S + quad * 8 + 32 * ks];
                #pragma unroll
                for (int mt = 0; mt < 2; ++mt)
                    sacc[mt][nt] = mfma16(taf[mt], xb, sacc[mt][nt]);
            }
        }

        // ---- Phase 4: A = softmax(gelu(S)); exp2-form ----
        #pragma unroll
        for (int mt = 0; mt < 2; ++mt)
            #pragma unroll
            for (int r = 0; r < 4; ++r) {
                float wv[8]; float rs = 0.f;
                #pragma unroll
                for (int nt = 0; nt < 8; ++nt) {
                    const float s  = sacc[mt][nt][r];
                    const float pl = fmaf(s * s, -0.10294310f, -2.3022157f);
                    const float em = __builtin_amdgcn_exp2f(s * pl);
                    const float rr = __builtin_amdgcn_rcpf(1.0f + em);
                    const float e  = __builtin_amdgcn_exp2f((s * 1.44269504f) * rr);
                    wv[nt] = e; rs += e;
                }
                rs += __shfl_xor(rs, 1); rs += __shfl_xor(rs, 2);
                rs += __shfl_xor(rs, 4); rs += __shfl_xor(rs, 8);
                const float inv = __builtin_amdgcn_rcpf(rs);
                #pragma unroll
                for (int nt = 0; nt < 8; ++nt) sacc[mt][nt][r] = wv[nt] * inv;
            }

        // ---- Phase 4a/5a: A_half <- vars 0..63 (wave-private), O += A*X ----
        #pragma unroll
        for (int mt = 0; mt < 2; ++mt)
            #pragma unroll
            for (int r = 0; r < 4; ++r) {
                const int R = 32 * w + 16 * mt + quad * 4 + r;
                _Float16* arow = &TA[R * TA_S + col];
                #pragma unroll
                for (int nt = 0; nt < 4; ++nt)
                    arow[nt * 16] = (_Float16)(sacc[mt][nt][r]);
            }

        floatx4 oacc[2][4];
        #pragma unroll
        for (int mt = 0; mt < 2; ++mt)
            #pragma unroll
            for (int nt = 0; nt < 4; ++nt) oacc[mt][nt] = (floatx4)0.0f;

        #pragma unroll
        for (int kh = 0; kh < 2; ++kh) {
            half8 aaf[2];
            #pragma unroll
            for (int mt = 0; mt < 2; ++mt)
                aaf[mt] = *(const half8*)&TA[(32 * w + 16 * mt + col) * TA_S + quad * 8 + 32 * kh];
            #pragma unroll
            for (int nt = 0; nt < 4; ++nt) {
                const half8 xb = *(const half8*)&Xt[(col + 16 * nt) * XT_S + quad * 8 + 32 * kh];
                #pragma unroll
                for (int mt = 0; mt < 2; ++mt)
                    oacc[mt][nt] = mfma16(aaf[mt], xb, oacc[mt][nt]);
            }
        }

        // ---- Phase 4b/5b: A_half <- vars 64..127, O += A*X ----
        #pragma unroll
        for (int mt = 0; mt < 2; ++mt)
            #pragma unroll
            for (int r = 0; r < 4; ++r) {
                const int R = 32 * w + 16 * mt + quad * 4 + r;
                _Float16* arow = &TA[R * TA_S + col];
                #pragma unroll
                for (int nt = 4; nt < 8; ++nt)
                    arow[(nt - 4) * 16] = (_Float16)(sacc[mt][nt][r]);
            }

        #pragma unroll
        for (int kh = 0; kh < 2; ++kh) {
            half8 aaf[2];
            #pragma unroll
            for (int mt = 0; mt < 2; ++mt)
                aaf[mt] = *(const half8*)&TA[(32 * w + 16 * mt + col) * TA_S + quad * 8 + 32 * kh];
            #pragma unroll
            for (int nt = 0; nt < 4; ++nt) {
                const half8 xb = *(const half8*)&Xt[(col + 16 * nt) * XT_S + quad * 8 + 32 * (kh + 2)];
                #pragma unroll
                for (int mt = 0; mt < 2; ++mt)
                    oacc[mt][nt] = mfma16(aaf[mt], xb, oacc[mt][nt]);
            }
        }

        // ---- Epilogue: direct stores (quad-wise 64B segments) ----
        #pragma unroll
        for (int mt = 0; mt < 2; ++mt)
            #pragma unroll
            for (int r = 0; r < 4; ++r) {
                const int i = 32 * w + 16 * mt + quad * 4 + r;
                float* orow = out + base + (size_t)i * RS + col;
                #pragma unroll
                for (int nt = 0; nt < 4; ++nt)
                    orow[nt * 16] = oacc[mt][nt][r];
            }
    }
}
} // namespace

extern "C" void kernel_launch(void* const* d_in, const int* in_sizes, int n_in,
                              void* d_out, int out_size, void* d_ws, size_t ws_size,
                              hipStream_t stream) {
    const float* x  = (const float*)d_in[0];
    const float* w1 = (const float*)d_in[1];
    const float* b1 = (const float*)d_in[2];
    const float* w2 = (const float*)d_in[3];
    const float* b2 = (const float*)d_in[4];
    float* out = (float*)d_out;

    _Float16* gxh = (_Float16*)d_ws;                  // 10240 B: [80][64] f16
    float* cf = (float*)((char*)d_ws + 10240);        // 4 B

    hipLaunchKernelGGL(pack_g, dim3(17), dim3(256), 0, stream,
                       w1, w2, b1, b2, gxh, cf);
    hipLaunchKernelGGL(space_graph_mfma9, dim3(NT2), dim3(256), 0, stream,
                       x, gxh, cf, out);
}

// Round 9
// 146.316 us; speedup vs baseline: 1.0848x; 1.0848x over previous
//
#include <hip/hip_runtime.h>
#include <math.h>

// spaceGraph via f16 MFMA, round 10.
// R9 post-mortem: pipeline was defeated by SCRATCH SPILL (WRITE 65->109MB,
// FETCH +20MB = spill traffic; pf[8]+sacc[2][8]+oacc ~ 140 regs live after
// B2). R10 = R9 with the liveness hump removed:
//  - P3..P5 split into two independent ROW-halves (mt=0,1): each half runs
//    S-init -> MFMA -> softmax -> A-store -> PV -> out-store to completion.
//    Rows are independent through softmax+PV, so this is a pure liveness
//    transform: peak = sacc[8](32) + oacc[4](16) + pf(32) + frags ~ 110 regs
//    < cap(~168 at 256thr,3blk). Cost: one extra taf/xb LDS read pass.
//  - everything else = R9: x read EXACTLY ONCE per tile (reg prefetch,
//    2 tiles/block, grid 1024); u,v via 80-row G MFMA (nt=4 block);
//    lgkm-only barriers, vmcnt NEVER drained between prefetch and use.

namespace {
constexpr int H = 8, NV = 128, HEAD = 64, B = 4, L = 8192;
constexpr int P = L / NV;        // 64
constexpr int D = H * HEAD;      // 512
constexpr int RS = P * D;        // 32768 floats between vars j -> j+1
constexpr int NT2 = (B * H * P) / 2;   // 1024 blocks, 2 tiles each

constexpr int XT_S = 136;        // Xt row stride (halfs); 64 rows (dims)
constexpr int XH_S = 72;         // Xh row stride (halfs); 128 rows (vars)
constexpr int TA_S = 72;         // T / A_half row stride (halfs); 128 rows

typedef _Float16 half8  __attribute__((ext_vector_type(8)));
typedef _Float16 half4h __attribute__((ext_vector_type(4)));
typedef _Float16 half2v __attribute__((ext_vector_type(2)));
typedef float    floatx4 __attribute__((ext_vector_type(4)));

__device__ __forceinline__ floatx4 mfma16(half8 a, half8 b, floatx4 c) {
    return __builtin_amdgcn_mfma_f32_16x16x32_f16(a, b, c, 0, 0, 0);
}

// u[128] in Xt row-pads of rows 0..31, v[128] in rows 32..63 (f32 slots).
__device__ __forceinline__ float& uslot(_Float16* xt, int j) {
    return ((float*)(xt + (j >> 2) * XT_S + 128))[j & 3];
}
__device__ __forceinline__ float& vslot(_Float16* xt, int j) {
    return ((float*)(xt + (32 + (j >> 2)) * XT_S + 128))[j & 3];
}

// ---- pre-pass: gxh[80][64] f16: rows 0..63 = G^T (gxh[e][d] = sum_n
// w1[n][d]w2[n][e]); row 64 = g2 (-> v, lane col0); row 65 = g1 (-> u, lane
// col1); rows 66..79 = 0.  cf = b1.b2 ----
__global__ __launch_bounds__(256) void pack_g(
    const float* __restrict__ w1, const float* __restrict__ w2,
    const float* __restrict__ b1, const float* __restrict__ b2,
    _Float16* __restrict__ gxh, float* __restrict__ cf)
{
    const int t = threadIdx.x;
    if (blockIdx.x == 16) {
        for (int z = t; z < 14 * 64; z += 256) gxh[66 * 64 + z] = (_Float16)0.f;
        if (t < 64) {
            float a = 0.f;
            #pragma unroll 8
            for (int n = 0; n < 64; ++n) a = fmaf(w2[n * 64 + t], b1[n], a);
            gxh[64 * 64 + t] = (_Float16)a;      // g2 -> v
        } else if (t < 128) {
            const int d = t - 64;
            float a = 0.f;
            #pragma unroll 8
            for (int n = 0; n < 64; ++n) a = fmaf(w1[n * 64 + d], b2[n], a);
            gxh[65 * 64 + d] = (_Float16)a;      // g1 -> u
        } else if (t == 128) {
            float a = 0.f;
            for (int n = 0; n < 64; ++n) a = fmaf(b1[n], b2[n], a);
            cf[0] = a;
        }
        return;
    }
    const int gid = blockIdx.x * 256 + t;
    const int d = gid & 63, e = gid >> 6;
    float a = 0.f;
    #pragma unroll 8
    for (int n = 0; n < 64; ++n) a = fmaf(w1[n * 64 + d], w2[n * 64 + e], a);
    gxh[e * 64 + d] = (_Float16)a;
}

__global__ __launch_bounds__(256, 3) void space_graph_mfma10(
    const float* __restrict__ x, const _Float16* __restrict__ gxh,
    const float* __restrict__ cf, float* __restrict__ out)
{
    // 64*136 + 128*72 + 128*72 = 27136 halfs = 54272 B -> 3 blocks/CU
    __shared__ _Float16 lds[64 * XT_S + NV * XH_S + NV * TA_S];
    _Float16* Xt = lds;                  // X^T [dim][var] (+u/v in row pads)
    _Float16* Xh = lds + 64 * XT_S;      // X   [var][dim] f16
    _Float16* TA = Xh + NV * XH_S;       // T (ph2-3), A_half (ph4-5)

    const int t    = threadIdx.x;
    const int lane = t & 63;
    const int w    = t >> 6;             // wave -> owns S/O rows 32w..32w+31
    const int col  = lane & 15;
    const int quad = lane >> 4;
    const int c    = t & 15;             // staging: float4 column
    const int ttv  = t >> 4;             // staging: row-pair selector 0..15

    const int blk = blockIdx.x;
    const int ti0 = blk, ti1 = blk + NT2;
    const size_t base0 =
        ((size_t)(ti0 >> 9) * L + (size_t)(ti0 & (P - 1))) * D + (size_t)((ti0 >> 6) & (H - 1)) * HEAD;
    const size_t base1 =
        ((size_t)(ti1 >> 9) * L + (size_t)(ti1 & (P - 1))) * D + (size_t)((ti1 >> 6) & (H - 1)) * HEAD;

    const float cc = cf[0];

    // ---- prefetch tile 0 staging loads into registers ----
    float4 pf[8];
    #pragma unroll
    for (int it = 0; it < 4; ++it) {
        const int j0 = 2 * (ttv + 16 * it);
        pf[2 * it]     = *(const float4*)(x + base0 + (size_t)j0 * RS + c * 4);
        pf[2 * it + 1] = *(const float4*)(x + base0 + (size_t)(j0 + 1) * RS + c * 4);
    }

    #pragma unroll
    for (int tile = 0; tile < 2; ++tile) {
        const size_t base = (tile == 0) ? base0 : base1;

        if (tile == 1) {   // B0: tile0's LDS readers done before overwrite
            asm volatile("s_waitcnt lgkmcnt(0)" ::: "memory");
            __builtin_amdgcn_s_barrier();
            __builtin_amdgcn_sched_barrier(0);
        }

        // ---- Stage: prefetched regs -> Xt (transposed) + Xh (row-major) ----
        #pragma unroll
        for (int it = 0; it < 4; ++it) {
            const int j0 = 2 * (ttv + 16 * it);
            const float4 v0 = pf[2 * it];
            const float4 v1 = pf[2 * it + 1];
            const float va[4] = {v0.x, v0.y, v0.z, v0.w};
            const float vb[4] = {v1.x, v1.y, v1.z, v1.w};
            half4h ra, rb;
            #pragma unroll
            for (int q = 0; q < 4; ++q) {
                const _Float16 ha = (_Float16)va[q];
                const _Float16 hb = (_Float16)vb[q];
                ra[q] = ha; rb[q] = hb;
                half2v pr; pr[0] = ha; pr[1] = hb;
                *(half2v*)&Xt[(4 * c + q) * XT_S + j0] = pr;
            }
            *(half4h*)&Xh[(size_t)j0 * XH_S + 4 * c] = ra;
            *(half4h*)&Xh[(size_t)(j0 + 1) * XH_S + 4 * c] = rb;
        }

        // ---- B1: staging visible to all waves (lgkm only) ----
        asm volatile("s_waitcnt lgkmcnt(0)" ::: "memory");
        __builtin_amdgcn_s_barrier();
        __builtin_amdgcn_sched_barrier(0);

        // ---- Phase 2: [T | v u] = Xh * [G | g2 g1]  (A-frags from LDS) ----
        {
            floatx4 tacc[2][5];
            #pragma unroll
            for (int mt = 0; mt < 2; ++mt)
                #pragma unroll
                for (int nt = 0; nt < 5; ++nt) tacc[mt][nt] = (floatx4)0.0f;

            half8 axf[2][2];
            #pragma unroll
            for (int ks = 0; ks < 2; ++ks)
                #pragma unroll
                for (int mt = 0; mt < 2; ++mt)
                    axf[mt][ks] = *(const half8*)&Xh[(32 * w + 16 * mt + col) * XH_S + quad * 8 + 32 * ks];

            #pragma unroll
            for (int ks = 0; ks < 2; ++ks)
                #pragma unroll
                for (int nt = 0; nt < 5; ++nt) {
                    const half8 gb8 = *(const half8*)&gxh[(col + 16 * nt) * HEAD + quad * 8 + 32 * ks];
                    #pragma unroll
                    for (int mt = 0; mt < 2; ++mt)
                        tacc[mt][nt] = mfma16(axf[mt][ks], gb8, tacc[mt][nt]);
                }

            // u/v (nt=4 block) -> Xt row-pad slots; T -> TA (wave-private rows)
            #pragma unroll
            for (int mt = 0; mt < 2; ++mt)
                #pragma unroll
                for (int r = 0; r < 4; ++r) {
                    const int R = 32 * w + 16 * mt + quad * 4 + r;
                    if (col == 0) vslot(Xt, R) = tacc[mt][4][r];
                    if (col == 1) uslot(Xt, R) = tacc[mt][4][r];
                    _Float16* trow = &TA[R * TA_S + col];
                    #pragma unroll
                    for (int nt = 0; nt < 4; ++nt)
                        trow[nt * 16] = (_Float16)(tacc[mt][nt][r]);
                }
        }

        // ---- B2: cross-wave v/T visible (lgkm only) ----
        asm volatile("s_waitcnt lgkmcnt(0)" ::: "memory");
        __builtin_amdgcn_s_barrier();
        __builtin_amdgcn_sched_barrier(0);

        // ---- issue tile1 prefetch: the ONLY global loads in flight; they
        // ride under both mt-halves (~2.5Kcy >> HBM latency) ----
        if (tile == 0) {
            #pragma unroll
            for (int it = 0; it < 4; ++it) {
                const int j0 = 2 * (ttv + 16 * it);
                pf[2 * it]     = *(const float4*)(x + base1 + (size_t)j0 * RS + c * 4);
                pf[2 * it + 1] = *(const float4*)(x + base1 + (size_t)(j0 + 1) * RS + c * 4);
            }
            __builtin_amdgcn_sched_barrier(0);
        }

        // ==== two independent row-halves: S -> softmax -> A -> PV -> store ====
        #pragma unroll
        for (int mt = 0; mt < 2; ++mt) {
            const int rbase = 32 * w + 16 * mt;

            // ---- P3: S = T*Xh^T + (u_i + v_j + c) ----
            float ucr[4];
            #pragma unroll
            for (int r = 0; r < 4; ++r)
                ucr[r] = uslot(Xt, rbase + quad * 4 + r) + cc;
            float vrow[8];
            #pragma unroll
            for (int nt = 0; nt < 8; ++nt) vrow[nt] = vslot(Xt, col + 16 * nt);

            floatx4 sacc[8];
            #pragma unroll
            for (int nt = 0; nt < 8; ++nt)
                #pragma unroll
                for (int r = 0; r < 4; ++r)
                    sacc[nt][r] = ucr[r] + vrow[nt];

            #pragma unroll
            for (int ks = 0; ks < 2; ++ks) {
                const half8 taf = *(const half8*)&TA[(rbase + col) * TA_S + quad * 8 + 32 * ks];
                #pragma unroll
                for (int nt = 0; nt < 8; ++nt) {
                    const half8 xb = *(const half8*)&Xh[(col + 16 * nt) * XH_S + quad * 8 + 32 * ks];
                    sacc[nt] = mfma16(taf, xb, sacc[nt]);
                }
            }

            // ---- P4: softmax(gelu(S)), exp2-form ----
            #pragma unroll
            for (int r = 0; r < 4; ++r) {
                float wv[8]; float rs = 0.f;
                #pragma unroll
                for (int nt = 0; nt < 8; ++nt) {
                    const float s  = sacc[nt][r];
                    const float pl = fmaf(s * s, -0.10294310f, -2.3022157f);
                    const float em = __builtin_amdgcn_exp2f(s * pl);
                    const float rr = __builtin_amdgcn_rcpf(1.0f + em);
                    const float e  = __builtin_amdgcn_exp2f((s * 1.44269504f) * rr);
                    wv[nt] = e; rs += e;
                }
                rs += __shfl_xor(rs, 1); rs += __shfl_xor(rs, 2);
                rs += __shfl_xor(rs, 4); rs += __shfl_xor(rs, 8);
                const float inv = __builtin_amdgcn_rcpf(rs);
                #pragma unroll
                for (int nt = 0; nt < 8; ++nt) sacc[nt][r] = wv[nt] * inv;
            }

            floatx4 oacc[4];
            #pragma unroll
            for (int nt = 0; nt < 4; ++nt) oacc[nt] = (floatx4)0.0f;

            // ---- A-store (j 0..63, wave-private rows) + PV-a ----
            #pragma unroll
            for (int r = 0; r < 4; ++r) {
                _Float16* arow = &TA[(rbase + quad * 4 + r) * TA_S + col];
                #pragma unroll
                for (int nt = 0; nt < 4; ++nt)
                    arow[nt * 16] = (_Float16)(sacc[nt][r]);
            }
            #pragma unroll
            for (int kh = 0; kh < 2; ++kh) {
                const half8 aaf = *(const half8*)&TA[(rbase + col) * TA_S + quad * 8 + 32 * kh];
                #pragma unroll
                for (int nt = 0; nt < 4; ++nt) {
                    const half8 xb = *(const half8*)&Xt[(col + 16 * nt) * XT_S + quad * 8 + 32 * kh];
                    oacc[nt] = mfma16(aaf, xb, oacc[nt]);
                }
            }

            // ---- A-store (j 64..127) + PV-b ----
            #pragma unroll
            for (int r = 0; r < 4; ++r) {
                _Float16* arow = &TA[(rbase + quad * 4 + r) * TA_S + col];
                #pragma unroll
                for (int nt = 4; nt < 8; ++nt)
                    arow[(nt - 4) * 16] = (_Float16)(sacc[nt][r]);
            }
            #pragma unroll
            for (int kh = 0; kh < 2; ++kh) {
                const half8 aaf = *(const half8*)&TA[(rbase + col) * TA_S + quad * 8 + 32 * kh];
                #pragma unroll
                for (int nt = 0; nt < 4; ++nt) {
                    const half8 xb = *(const half8*)&Xt[(col + 16 * nt) * XT_S + quad * 8 + 32 * (kh + 2)];
                    oacc[nt] = mfma16(aaf, xb, oacc[nt]);
                }
            }

            // ---- out-store for this half's rows ----
            #pragma unroll
            for (int r = 0; r < 4; ++r) {
                float* orow = out + base + (size_t)(rbase + quad * 4 + r) * RS + col;
                #pragma unroll
                for (int nt = 0; nt < 4; ++nt)
                    orow[nt * 16] = oacc[nt][r];
            }
        }
    }
}
} // namespace

extern "C" void kernel_launch(void* const* d_in, const int* in_sizes, int n_in,
                              void* d_out, int out_size, void* d_ws, size_t ws_size,
                              hipStream_t stream) {
    const float* x  = (const float*)d_in[0];
    const float* w1 = (const float*)d_in[1];
    const float* b1 = (const float*)d_in[2];
    const float* w2 = (const float*)d_in[3];
    const float* b2 = (const float*)d_in[4];
    float* out = (float*)d_out;

    _Float16* gxh = (_Float16*)d_ws;                  // 10240 B: [80][64] f16
    float* cf = (float*)((char*)d_ws + 10240);        // 4 B

    hipLaunchKernelGGL(pack_g, dim3(17), dim3(256), 0, stream,
                       w1, w2, b1, b2, gxh, cf);
    hipLaunchKernelGGL(space_graph_mfma10, dim3(NT2), dim3(256), 0, stream,
                       x, gxh, cf, out);
}

// Round 10
// 141.320 us; speedup vs baseline: 1.1232x; 1.0354x over previous
//
#include <hip/hip_runtime.h>
#include <math.h>

// spaceGraph via f16 MFMA, round 11.
// Ledger R5..R10: R5=50.7us best; occupancy x2 (R6) flat; conflict -33% (R7)
// flat; prefetch pipelines (R8/R9/R10) net-negative (double-read / spill /
// barrier overhead). Conclusion: R5's 1-barrier structure is the optimum;
// remaining stall is structural. R11 = R5 skeleton + the two VALU cuts that
// were correctness-proven in later rounds (separable from what made those
// rounds slow):
//  - u,v via a 5th MFMA column-block (R9/R10): gxh[80][64] with row64=g2
//    (-> v at lane col0), row65=g1 (-> u at lane col1); kills 64 dual-FMA
//    dots + g-loads + shfls per thread. u,v -> Xt row-pad f32 slots.
//  - exp2-form softmax (R6/R10): -2 and log2e folded into constants.
// Everything else IDENTICAL to R5: 256 thr / 4 waves x 32 rows, ONE barrier,
// P2 A-frags from L1-hot global, padded strides, 54272B LDS -> 3 blocks/CU.

namespace {
constexpr int H = 8, NV = 128, HEAD = 64, B = 4, L = 8192;
constexpr int P = L / NV;        // 64
constexpr int D = H * HEAD;      // 512
constexpr int RS = P * D;        // 32768 floats between vars j -> j+1

constexpr int XT_S = 136;        // Xt row stride (halfs); 64 rows (dims)
constexpr int XH_S = 72;         // Xh row stride (halfs); 128 rows (vars)
constexpr int TA_S = 72;         // T / A_half row stride (halfs); 128 rows

typedef _Float16 half8  __attribute__((ext_vector_type(8)));
typedef _Float16 half4h __attribute__((ext_vector_type(4)));
typedef _Float16 half2v __attribute__((ext_vector_type(2)));
typedef __fp16   fp16x2 __attribute__((ext_vector_type(2)));
typedef float    floatx4 __attribute__((ext_vector_type(4)));

__device__ __forceinline__ floatx4 mfma16(half8 a, half8 b, floatx4 c) {
    return __builtin_amdgcn_mfma_f32_16x16x32_f16(a, b, c, 0, 0, 0);
}

__device__ __forceinline__ half8 cvt8(float4 a, float4 b) {
    fp16x2 p0 = __builtin_amdgcn_cvt_pkrtz(a.x, a.y);
    fp16x2 p1 = __builtin_amdgcn_cvt_pkrtz(a.z, a.w);
    fp16x2 p2 = __builtin_amdgcn_cvt_pkrtz(b.x, b.y);
    fp16x2 p3 = __builtin_amdgcn_cvt_pkrtz(b.z, b.w);
    half8 r;
    r[0] = (_Float16)p0[0]; r[1] = (_Float16)p0[1];
    r[2] = (_Float16)p1[0]; r[3] = (_Float16)p1[1];
    r[4] = (_Float16)p2[0]; r[5] = (_Float16)p2[1];
    r[6] = (_Float16)p3[0]; r[7] = (_Float16)p3[1];
    return r;
}

// u[128] in Xt row-pads of rows 0..31, v[128] in rows 32..63 (f32 slots).
__device__ __forceinline__ float& uslot(_Float16* xt, int j) {
    return ((float*)(xt + (j >> 2) * XT_S + 128))[j & 3];
}
__device__ __forceinline__ float& vslot(_Float16* xt, int j) {
    return ((float*)(xt + (32 + (j >> 2)) * XT_S + 128))[j & 3];
}

// ---- pre-pass: gxh[80][64] f16: rows 0..63 = G^T (gxh[e][d] = sum_n
// w1[n][d]w2[n][e]); row 64 = g2 (-> v, lane col0); row 65 = g1 (-> u, lane
// col1); rows 66..79 = 0.  cf = b1.b2 ----
__global__ __launch_bounds__(256) void pack_g(
    const float* __restrict__ w1, const float* __restrict__ w2,
    const float* __restrict__ b1, const float* __restrict__ b2,
    _Float16* __restrict__ gxh, float* __restrict__ cf)
{
    const int t = threadIdx.x;
    if (blockIdx.x == 16) {
        for (int z = t; z < 14 * 64; z += 256) gxh[66 * 64 + z] = (_Float16)0.f;
        if (t < 64) {
            float a = 0.f;
            #pragma unroll 8
            for (int n = 0; n < 64; ++n) a = fmaf(w2[n * 64 + t], b1[n], a);
            gxh[64 * 64 + t] = (_Float16)a;      // g2 -> v
        } else if (t < 128) {
            const int d = t - 64;
            float a = 0.f;
            #pragma unroll 8
            for (int n = 0; n < 64; ++n) a = fmaf(w1[n * 64 + d], b2[n], a);
            gxh[65 * 64 + d] = (_Float16)a;      // g1 -> u
        } else if (t == 128) {
            float a = 0.f;
            for (int n = 0; n < 64; ++n) a = fmaf(b1[n], b2[n], a);
            cf[0] = a;
        }
        return;
    }
    const int gid = blockIdx.x * 256 + t;
    const int d = gid & 63, e = gid >> 6;
    float a = 0.f;
    #pragma unroll 8
    for (int n = 0; n < 64; ++n) a = fmaf(w1[n * 64 + d], w2[n * 64 + e], a);
    gxh[e * 64 + d] = (_Float16)a;
}

__global__ __launch_bounds__(256, 3) void space_graph_mfma11(
    const float* __restrict__ x, const _Float16* __restrict__ gxh,
    const float* __restrict__ cf, float* __restrict__ out)
{
    // 64*136 + 128*72 + 128*72 = 27136 halfs = 54272 B -> 3 blocks/CU
    __shared__ _Float16 lds[64 * XT_S + NV * XH_S + NV * TA_S];
    _Float16* Xt = lds;                  // X^T [dim][var] (+u/v in row pads)
    _Float16* Xh = lds + 64 * XT_S;      // X   [var][dim] f16 (phase 3 B-op)
    _Float16* TA = Xh + NV * XH_S;       // T (ph2-3), A_half (ph4-5)

    const int t    = threadIdx.x;
    const int lane = t & 63;
    const int w    = t >> 6;             // wave -> owns S/O rows 32w..32w+31
    const int col  = lane & 15;
    const int quad = lane >> 4;

    const int blk = blockIdx.x;
    const int p = blk & (P - 1);
    const int h = (blk >> 6) & (H - 1);
    const int b = blk >> 9;
    const size_t base = ((size_t)b * L + (size_t)p) * D + (size_t)h * HEAD;

    const float cc = cf[0];

    // ---- Phase 1: build Xt (transposed) AND Xh (row-major) in f16 ----
    {
        const int c  = t & 15;           // float4 column
        const int tt = t >> 4;
        #pragma unroll
        for (int it = 0; it < 4; ++it) {
            const int j0 = 2 * (tt + 16 * it);
            const float4 v0 = *(const float4*)(x + base + (size_t)j0 * RS + c * 4);
            const float4 v1 = *(const float4*)(x + base + (size_t)(j0 + 1) * RS + c * 4);
            const float va[4] = {v0.x, v0.y, v0.z, v0.w};
            const float vb[4] = {v1.x, v1.y, v1.z, v1.w};
            half4h ra, rb;
            #pragma unroll
            for (int q = 0; q < 4; ++q) {
                const _Float16 ha = (_Float16)va[q];
                const _Float16 hb = (_Float16)vb[q];
                ra[q] = ha; rb[q] = hb;
                half2v pr; pr[0] = ha; pr[1] = hb;
                *(half2v*)&Xt[(4 * c + q) * XT_S + j0] = pr;
            }
            *(half4h*)&Xh[(size_t)j0 * XH_S + 4 * c] = ra;
            *(half4h*)&Xh[(size_t)(j0 + 1) * XH_S + 4 * c] = rb;
        }
    }

    // ---- Phase 2: [T | v u] = X * [G | g2 g1]; A-frags from L1-hot global ----
    floatx4 tacc[2][5];
    #pragma unroll
    for (int mt = 0; mt < 2; ++mt)
        #pragma unroll
        for (int nt = 0; nt < 5; ++nt) tacc[mt][nt] = (floatx4)0.0f;

    half8 axf[2][2];
    #pragma unroll
    for (int ks = 0; ks < 2; ++ks)
        #pragma unroll
        for (int mt = 0; mt < 2; ++mt) {
            const int row = 32 * w + 16 * mt + col;
            const float* src = x + base + (size_t)row * RS + quad * 8 + 32 * ks;
            axf[mt][ks] = cvt8(*(const float4*)src, *(const float4*)(src + 4));
        }

    #pragma unroll
    for (int ks = 0; ks < 2; ++ks)
        #pragma unroll
        for (int nt = 0; nt < 5; ++nt) {
            const half8 gb8 = *(const half8*)&gxh[(col + 16 * nt) * HEAD + quad * 8 + 32 * ks];
            #pragma unroll
            for (int mt = 0; mt < 2; ++mt)
                tacc[mt][nt] = mfma16(axf[mt][ks], gb8, tacc[mt][nt]);
        }

    // u/v (nt=4 column block: n=64 -> g2 -> v at col0, n=65 -> g1 -> u at col1)
    // -> Xt row-pad f32 slots; T -> TA (wave-private rows)
    #pragma unroll
    for (int mt = 0; mt < 2; ++mt)
        #pragma unroll
        for (int r = 0; r < 4; ++r) {
            const int R = 32 * w + 16 * mt + quad * 4 + r;
            if (col == 0) vslot(Xt, R) = tacc[mt][4][r];
            if (col == 1) uslot(Xt, R) = tacc[mt][4][r];
            _Float16* trow = &TA[R * TA_S + col];
            #pragma unroll
            for (int nt = 0; nt < 4; ++nt)
                trow[nt * 16] = (_Float16)(tacc[mt][nt][r]);
        }
    __syncthreads();   // the ONLY barrier: covers Xt/Xh (ph3/5) and u/v (ph3)

    // ---- Phase 3: S = T*Xh^T + (u_i + v_j + c) via accumulator init ----
    float ucr[2][4];
    #pragma unroll
    for (int mt = 0; mt < 2; ++mt)
        #pragma unroll
        for (int r = 0; r < 4; ++r)
            ucr[mt][r] = uslot(Xt, 32 * w + 16 * mt + quad * 4 + r) + cc;
    float vrow[8];
    #pragma unroll
    for (int nt = 0; nt < 8; ++nt) vrow[nt] = vslot(Xt, col + 16 * nt);

    floatx4 sacc[2][8];
    #pragma unroll
    for (int mt = 0; mt < 2; ++mt)
        #pragma unroll
        for (int nt = 0; nt < 8; ++nt)
            #pragma unroll
            for (int r = 0; r < 4; ++r)
                sacc[mt][nt][r] = ucr[mt][r] + vrow[nt];

    #pragma unroll
    for (int ks = 0; ks < 2; ++ks) {
        half8 taf[2];
        #pragma unroll
        for (int mt = 0; mt < 2; ++mt)
            taf[mt] = *(const half8*)&TA[(32 * w + 16 * mt + col) * TA_S + quad * 8 + 32 * ks];
        #pragma unroll
        for (int nt = 0; nt < 8; ++nt) {
            const half8 xb = *(const half8*)&Xh[(col + 16 * nt) * XH_S + quad * 8 + 32 * ks];
            #pragma unroll
            for (int mt = 0; mt < 2; ++mt)
                sacc[mt][nt] = mfma16(taf[mt], xb, sacc[mt][nt]);
        }
    }

    // ---- Phase 4: A = softmax(gelu(S)); exp2-form, folded constants ----
    #pragma unroll
    for (int mt = 0; mt < 2; ++mt)
        #pragma unroll
        for (int r = 0; r < 4; ++r) {
            float wv[8]; float rs = 0.f;
            #pragma unroll
            for (int nt = 0; nt < 8; ++nt) {
                const float s  = sacc[mt][nt][r];
                const float pl = fmaf(s * s, -0.10294310f, -2.3022157f);
                const float em = __builtin_amdgcn_exp2f(s * pl);
                const float rr = __builtin_amdgcn_rcpf(1.0f + em);
                const float e  = __builtin_amdgcn_exp2f((s * 1.44269504f) * rr);
                wv[nt] = e; rs += e;
            }
            rs += __shfl_xor(rs, 1); rs += __shfl_xor(rs, 2);
            rs += __shfl_xor(rs, 4); rs += __shfl_xor(rs, 8);
            const float inv = __builtin_amdgcn_rcpf(rs);
            #pragma unroll
            for (int nt = 0; nt < 8; ++nt) sacc[mt][nt][r] = wv[nt] * inv;
        }

    // ---- Phase 4a/5a: A_half <- vars 0..63 (wave-private rows), O += A*X ----
    #pragma unroll
    for (int mt = 0; mt < 2; ++mt)
        #pragma unroll
        for (int r = 0; r < 4; ++r) {
            const int R = 32 * w + 16 * mt + quad * 4 + r;
            _Float16* arow = &TA[R * TA_S + col];
            #pragma unroll
            for (int nt = 0; nt < 4; ++nt)
                arow[nt * 16] = (_Float16)(sacc[mt][nt][r]);
        }

    floatx4 oacc[2][4];
    #pragma unroll
    for (int mt = 0; mt < 2; ++mt)
        #pragma unroll
        for (int nt = 0; nt < 4; ++nt) oacc[mt][nt] = (floatx4)0.0f;

    #pragma unroll
    for (int kh = 0; kh < 2; ++kh) {
        half8 aaf[2];
        #pragma unroll
        for (int mt = 0; mt < 2; ++mt)
            aaf[mt] = *(const half8*)&TA[(32 * w + 16 * mt + col) * TA_S + quad * 8 + 32 * kh];
        #pragma unroll
        for (int nt = 0; nt < 4; ++nt) {
            const half8 xb = *(const half8*)&Xt[(col + 16 * nt) * XT_S + quad * 8 + 32 * kh];
            #pragma unroll
            for (int mt = 0; mt < 2; ++mt)
                oacc[mt][nt] = mfma16(aaf[mt], xb, oacc[mt][nt]);
        }
    }

    // ---- Phase 4b/5b: A_half <- vars 64..127, O += A*X ----
    #pragma unroll
    for (int mt = 0; mt < 2; ++mt)
        #pragma unroll
        for (int r = 0; r < 4; ++r) {
            const int R = 32 * w + 16 * mt + quad * 4 + r;
            _Float16* arow = &TA[R * TA_S + col];
            #pragma unroll
            for (int nt = 4; nt < 8; ++nt)
                arow[(nt - 4) * 16] = (_Float16)(sacc[mt][nt][r]);
        }

    #pragma unroll
    for (int kh = 0; kh < 2; ++kh) {
        half8 aaf[2];
        #pragma unroll
        for (int mt = 0; mt < 2; ++mt)
            aaf[mt] = *(const half8*)&TA[(32 * w + 16 * mt + col) * TA_S + quad * 8 + 32 * kh];
        #pragma unroll
        for (int nt = 0; nt < 4; ++nt) {
            const half8 xb = *(const half8*)&Xt[(col + 16 * nt) * XT_S + quad * 8 + 32 * (kh + 2)];
            #pragma unroll
            for (int mt = 0; mt < 2; ++mt)
                oacc[mt][nt] = mfma16(aaf[mt], xb, oacc[mt][nt]);
        }
    }

    // ---- Epilogue: direct stores (quad-wise 64B segments) ----
    #pragma unroll
    for (int mt = 0; mt < 2; ++mt)
        #pragma unroll
        for (int r = 0; r < 4; ++r) {
            const int i = 32 * w + 16 * mt + quad * 4 + r;
            float* orow = out + base + (size_t)i * RS + col;
            #pragma unroll
            for (int nt = 0; nt < 4; ++nt)
                orow[nt * 16] = oacc[mt][nt][r];
        }
}
} // namespace

extern "C" void kernel_launch(void* const* d_in, const int* in_sizes, int n_in,
                              void* d_out, int out_size, void* d_ws, size_t ws_size,
                              hipStream_t stream) {
    const float* x  = (const float*)d_in[0];
    const float* w1 = (const float*)d_in[1];
    const float* b1 = (const float*)d_in[2];
    const float* w2 = (const float*)d_in[3];
    const float* b2 = (const float*)d_in[4];
    float* out = (float*)d_out;

    _Float16* gxh = (_Float16*)d_ws;                  // 10240 B: [80][64] f16
    float* cf = (float*)((char*)d_ws + 10240);        // 4 B

    hipLaunchKernelGGL(pack_g, dim3(17), dim3(256), 0, stream,
                       w1, w2, b1, b2, gxh, cf);
    hipLaunchKernelGGL(space_graph_mfma11, dim3(B * H * P), dim3(256), 0, stream,
                       x, gxh, cf, out);
}